// Round 1
// baseline (295.804 us; speedup 1.0000x reference)
//
#include <hip/hip_runtime.h>

// Problem constants (match reference)
#define NB 4
#define LL 2048
#define NH 12
#define DD 64
#define CB 64              // our chunk size (not the reference's 128; math identical)
#define NG (LL/CB)         // 32 chunks
#define SS (DD*DD + DD)    // per-chunk state: kv[64][64] + ksum[64] = 4160 floats

__device__ __forceinline__ float phi(float x) {
    // elu(x)+1 : x+1 for x>0, exp(x) for x<=0
    return x > 0.0f ? x + 1.0f : __expf(x);
}

// Kernel 1: per-chunk kv outer-product sums + k column sums -> ws (inclusive, per chunk)
__global__ __launch_bounds__(256) void la_chunk_sums(
    const float* __restrict__ kin, const float* __restrict__ vin,
    float* __restrict__ ws)
{
    __shared__ float kf[CB*DD];
    __shared__ float vv[CB*DD];
    const int bid = blockIdx.x;
    const int g = bid & (NG-1);
    const int h = (bid / NG) % NH;
    const int n = bid / (NG*NH);
    const int t = threadIdx.x;
    const int l0 = g * CB;

    // stage phi(k) and v into LDS (coalesced-ish float4 loads)
    for (int i = t; i < CB*DD/4; i += 256) {
        const int row = i >> 4, c4 = i & 15;
        const size_t gidx = ((size_t)((n*LL + l0 + row)*NH + h))*DD + c4*4;
        float4 kk = *(const float4*)(kin + gidx);
        float4 vl = *(const float4*)(vin + gidx);
        kk.x = phi(kk.x); kk.y = phi(kk.y); kk.z = phi(kk.z); kk.w = phi(kk.w);
        *(float4*)(kf + row*DD + c4*4) = kk;
        *(float4*)(vv + row*DD + c4*4) = vl;
    }
    __syncthreads();

    // thread t -> column m = t&63, d-group dg = t>>6 (wave-uniform), 16 d's each
    const int m  = t & 63;
    const int dg = t >> 6;
    float acc[16];
    #pragma unroll
    for (int i = 0; i < 16; ++i) acc[i] = 0.f;

    #pragma unroll 1
    for (int c = 0; c < CB; ++c) {
        const float vval = vv[c*DD + m];                       // lane-consecutive, conflict-free
        const float4* kr = (const float4*)(kf + c*DD + dg*16); // wave-uniform broadcast
        #pragma unroll
        for (int i4 = 0; i4 < 4; ++i4) {
            const float4 kk = kr[i4];
            acc[i4*4+0] += kk.x * vval;
            acc[i4*4+1] += kk.y * vval;
            acc[i4*4+2] += kk.z * vval;
            acc[i4*4+3] += kk.w * vval;
        }
    }
    float* st = ws + (size_t)bid * SS;
    #pragma unroll
    for (int i = 0; i < 16; ++i)
        st[(dg*16 + i)*DD + m] = acc[i];                       // coalesced stores

    if (t < 64) {
        float s = 0.f;
        #pragma unroll 1
        for (int c = 0; c < CB; ++c) s += kf[c*DD + t];
        st[DD*DD + t] = s;
    }
}

// Kernel 2: exclusive prefix scan over chunks (per n,h), in place
__global__ __launch_bounds__(256) void la_scan(float* __restrict__ ws)
{
    float* base = ws + (size_t)blockIdx.x * NG * SS;
    for (int e = threadIdx.x; e < SS; e += 256) {
        float run = 0.f;
        #pragma unroll 1
        for (int gg = 0; gg < NG; ++gg) {
            float* p = base + (size_t)gg * SS + e;
            const float tmp = *p;
            *p = run;          // exclusive: state entering chunk gg
            run += tmp;
        }
    }
}

// Kernel 3: per-chunk output. 64 threads = 64 rows; q row in registers.
__global__ __launch_bounds__(64) void la_output(
    const float* __restrict__ qin, const float* __restrict__ kin,
    const float* __restrict__ vin, const float* __restrict__ ws,
    float* __restrict__ out)
{
    __shared__ float kf[CB*DD];
    __shared__ float vv[CB*DD];
    __shared__ float Sx[DD*DD];
    __shared__ float ksx[DD];
    const int bid = blockIdx.x;
    const int g = bid & (NG-1);
    const int h = (bid / NG) % NH;
    const int n = bid / (NG*NH);
    const int t = threadIdx.x;   // row within chunk
    const int l0 = g * CB;

    for (int i = t; i < CB*DD/4; i += 64) {
        const int row = i >> 4, c4 = i & 15;
        const size_t gidx = ((size_t)((n*LL + l0 + row)*NH + h))*DD + c4*4;
        float4 kk = *(const float4*)(kin + gidx);
        float4 vl = *(const float4*)(vin + gidx);
        kk.x = phi(kk.x); kk.y = phi(kk.y); kk.z = phi(kk.z); kk.w = phi(kk.w);
        *(float4*)(kf + row*DD + c4*4) = kk;
        *(float4*)(vv + row*DD + c4*4) = vl;
    }
    const float* st = ws + (size_t)bid * SS;
    for (int i = t; i < DD*DD/4; i += 64) {
        *(float4*)(Sx + i*4) = *(const float4*)(st + i*4);
    }
    ksx[t] = st[DD*DD + t];

    // q row -> registers with phi applied
    float qreg[DD];
    {
        const size_t qidx = ((size_t)((n*LL + l0 + t)*NH + h))*DD;
        #pragma unroll
        for (int d4 = 0; d4 < 16; ++d4) {
            const float4 qq = *(const float4*)(qin + qidx + d4*4);
            qreg[d4*4+0] = phi(qq.x);
            qreg[d4*4+1] = phi(qq.y);
            qreg[d4*4+2] = phi(qq.z);
            qreg[d4*4+3] = phi(qq.w);
        }
    }
    __syncthreads();

    float acc[DD];
    #pragma unroll
    for (int mm = 0; mm < DD; ++mm) acc[mm] = 0.f;
    float z = 0.f;

    // intra-chunk causal part: rows r <= t
    #pragma unroll 1
    for (int r = 0; r < CB; ++r) {
        const float4* kr = (const float4*)(kf + r*DD);   // broadcast reads
        float s = 0.f;
        #pragma unroll
        for (int d4 = 0; d4 < 16; ++d4) {
            const float4 kk = kr[d4];
            s += qreg[d4*4+0]*kk.x + qreg[d4*4+1]*kk.y
               + qreg[d4*4+2]*kk.z + qreg[d4*4+3]*kk.w;
        }
        if (r <= t) {
            z += s;
            const float4* vr = (const float4*)(vv + r*DD);
            #pragma unroll
            for (int m4 = 0; m4 < 16; ++m4) {
                const float4 vx = vr[m4];
                acc[m4*4+0] += s*vx.x;
                acc[m4*4+1] += s*vx.y;
                acc[m4*4+2] += s*vx.z;
                acc[m4*4+3] += s*vx.w;
            }
        }
    }

    // inter part: acc += qreg @ Sx ; z += qreg . ksum_excl
    // fully unrolled so qreg/acc indices stay compile-time (no scratch)
    #pragma unroll
    for (int d4 = 0; d4 < 16; ++d4) {
        const float4 ks4 = *(const float4*)(ksx + d4*4);
        z += qreg[d4*4+0]*ks4.x + qreg[d4*4+1]*ks4.y
           + qreg[d4*4+2]*ks4.z + qreg[d4*4+3]*ks4.w;
        #pragma unroll
        for (int j = 0; j < 4; ++j) {
            const int d = d4*4 + j;
            const float qd = qreg[d];
            const float4* sr = (const float4*)(Sx + d*DD);
            #pragma unroll
            for (int m4 = 0; m4 < 16; ++m4) {
                const float4 sv = sr[m4];
                acc[m4*4+0] += qd*sv.x;
                acc[m4*4+1] += qd*sv.y;
                acc[m4*4+2] += qd*sv.z;
                acc[m4*4+3] += qd*sv.w;
            }
        }
    }

    const float zinv = 1.0f / (z + 1e-6f);
    float* orow = out + ((size_t)((n*LL + l0 + t)*NH + h))*DD;
    #pragma unroll
    for (int m4 = 0; m4 < 16; ++m4) {
        float4 o;
        o.x = acc[m4*4+0]*zinv;
        o.y = acc[m4*4+1]*zinv;
        o.z = acc[m4*4+2]*zinv;
        o.w = acc[m4*4+3]*zinv;
        *(float4*)(orow + m4*4) = o;
    }
}

extern "C" void kernel_launch(void* const* d_in, const int* in_sizes, int n_in,
                              void* d_out, int out_size, void* d_ws, size_t ws_size,
                              hipStream_t stream) {
    const float* q = (const float*)d_in[0];
    const float* k = (const float*)d_in[1];
    const float* v = (const float*)d_in[2];
    float* out = (float*)d_out;
    float* ws  = (float*)d_ws;   // needs NB*NH*NG*SS*4 = ~24.4 MiB

    const int nblk = NB * NH * NG;   // 1536
    la_chunk_sums<<<nblk, 256, 0, stream>>>(k, v, ws);
    la_scan<<<NB*NH, 256, 0, stream>>>(ws);
    la_output<<<nblk, 64, 0, stream>>>(q, k, v, ws, out);
}

// Round 2
// 95.984 us; speedup vs baseline: 3.0818x; 3.0818x over previous
//
#include <hip/hip_runtime.h>

// Problem constants (match reference)
#define NB 4
#define LL 2048
#define NH 12
#define DD 64
#define CB 64              // our chunk size (math identical to reference's 128)
#define NG (LL/CB)         // 32 chunks
#define SS (DD*DD + DD)    // per-chunk state: kv[64][64] + ksum[64] = 4160 floats
#define DP (DD+1)          // padded stride for lane=row LDS access

__device__ __forceinline__ float phi(float x) {
    // elu(x)+1 : x+1 for x>0, exp(x) for x<=0
    return x > 0.0f ? x + 1.0f : __expf(x);
}

// Kernel 1: per-chunk kv outer-product sums + k column sums -> ws (inclusive, per chunk)
__global__ __launch_bounds__(256) void la_chunk_sums(
    const float* __restrict__ kin, const float* __restrict__ vin,
    float* __restrict__ ws)
{
    __shared__ float kf[CB*DD];
    __shared__ float vv[CB*DD];
    const int bid = blockIdx.x;
    const int g = bid & (NG-1);
    const int h = (bid / NG) % NH;
    const int n = bid / (NG*NH);
    const int t = threadIdx.x;
    const int l0 = g * CB;

    for (int i = t; i < CB*DD/4; i += 256) {
        const int row = i >> 4, c4 = i & 15;
        const size_t gidx = ((size_t)((n*LL + l0 + row)*NH + h))*DD + c4*4;
        float4 kk = *(const float4*)(kin + gidx);
        float4 vl = *(const float4*)(vin + gidx);
        kk.x = phi(kk.x); kk.y = phi(kk.y); kk.z = phi(kk.z); kk.w = phi(kk.w);
        *(float4*)(kf + row*DD + c4*4) = kk;
        *(float4*)(vv + row*DD + c4*4) = vl;
    }
    __syncthreads();

    // thread t -> column m = t&63, d-group dg = t>>6 (wave-uniform), 16 d's each
    const int m  = t & 63;
    const int dg = t >> 6;
    float acc[16];
    #pragma unroll
    for (int i = 0; i < 16; ++i) acc[i] = 0.f;

    #pragma unroll 4
    for (int c = 0; c < CB; ++c) {
        const float vval = vv[c*DD + m];                       // lane-consecutive (2-way, free)
        const float4* kr = (const float4*)(kf + c*DD + dg*16); // wave-uniform broadcast
        #pragma unroll
        for (int i4 = 0; i4 < 4; ++i4) {
            const float4 kk = kr[i4];
            acc[i4*4+0] += kk.x * vval;
            acc[i4*4+1] += kk.y * vval;
            acc[i4*4+2] += kk.z * vval;
            acc[i4*4+3] += kk.w * vval;
        }
    }
    float* st = ws + (size_t)bid * SS;
    #pragma unroll
    for (int i = 0; i < 16; ++i)
        st[(dg*16 + i)*DD + m] = acc[i];                       // coalesced stores

    if (t < 64) {
        float s = 0.f;
        #pragma unroll 4
        for (int c = 0; c < CB; ++c) s += kf[c*DD + t];
        st[DD*DD + t] = s;
    }
}

// Kernel 2: exclusive prefix scan over chunks (per n,h), in place.
// grid = NB*NH*5 blocks; each block owns 256 float4 slots of one (n,h).
__global__ __launch_bounds__(256) void la_scan(float* __restrict__ ws)
{
    const int nh = blockIdx.x / 5;
    const int sl = blockIdx.x % 5;
    const int t4 = sl*256 + threadIdx.x;            // float4 slot within SS
    if (t4 >= SS/4) return;
    float* base = ws + (size_t)nh * NG * SS + (size_t)t4 * 4;

    float4 run = make_float4(0.f, 0.f, 0.f, 0.f);
    #pragma unroll 1
    for (int g4 = 0; g4 < NG; g4 += 4) {
        // batch 4 independent loads ahead of the dependent add/store chain
        float4 a0 = *(float4*)(base + (size_t)(g4+0)*SS);
        float4 a1 = *(float4*)(base + (size_t)(g4+1)*SS);
        float4 a2 = *(float4*)(base + (size_t)(g4+2)*SS);
        float4 a3 = *(float4*)(base + (size_t)(g4+3)*SS);
        *(float4*)(base + (size_t)(g4+0)*SS) = run;
        run.x += a0.x; run.y += a0.y; run.z += a0.z; run.w += a0.w;
        *(float4*)(base + (size_t)(g4+1)*SS) = run;
        run.x += a1.x; run.y += a1.y; run.z += a1.z; run.w += a1.w;
        *(float4*)(base + (size_t)(g4+2)*SS) = run;
        run.x += a2.x; run.y += a2.y; run.z += a2.z; run.w += a2.w;
        *(float4*)(base + (size_t)(g4+3)*SS) = run;
        run.x += a3.x; run.y += a3.y; run.z += a3.z; run.w += a3.w;
    }
}

// Kernel 3: per-chunk output, 256 threads (4 waves). Scores shared via LDS.
__global__ __launch_bounds__(256) void la_output(
    const float* __restrict__ qin, const float* __restrict__ kin,
    const float* __restrict__ vin, const float* __restrict__ ws,
    float* __restrict__ out)
{
    __shared__ float sq[CB*DP];     // phi(q) tile, then scores S (both lane=row padded)
    __shared__ float buf[CB*DP];    // phi(k) tile -> S_excl (stride DD) -> out stage (stride DP)
    __shared__ float vv[CB*DD];
    __shared__ float ksx[DD];
    const int bid = blockIdx.x;
    const int g = bid & (NG-1);
    const int h = (bid / NG) % NH;
    const int n = bid / (NG*NH);
    const int t = threadIdx.x;
    const int l0 = g * CB;
    const int lane = t & 63;        // query row (phase 1) == output row (phase 2)
    const int grp  = t >> 6;        // wave id 0..3 (wave-uniform)

    // ---- phase 0: stage phi(k), v, phi(q); prefetch S_excl slice to regs ----
    for (int i = t; i < CB*DD/4; i += 256) {
        const int row = i >> 4, c4 = i & 15;
        const size_t gidx = ((size_t)((n*LL + l0 + row)*NH + h))*DD + c4*4;
        float4 kk = *(const float4*)(kin + gidx);
        float4 vl = *(const float4*)(vin + gidx);
        float4 qq = *(const float4*)(qin + gidx);
        kk.x = phi(kk.x); kk.y = phi(kk.y); kk.z = phi(kk.z); kk.w = phi(kk.w);
        qq.x = phi(qq.x); qq.y = phi(qq.y); qq.z = phi(qq.z); qq.w = phi(qq.w);
        *(float4*)(buf + row*DD + c4*4) = kk;
        *(float4*)(vv  + row*DD + c4*4) = vl;
        // padded stride -> scalar stores (banks (row+4*c4+j)%32: 2-way, free)
        sq[row*DP + c4*4 + 0] = qq.x;
        sq[row*DP + c4*4 + 1] = qq.y;
        sq[row*DP + c4*4 + 2] = qq.z;
        sq[row*DP + c4*4 + 3] = qq.w;
    }
    const float* stt = ws + (size_t)bid * SS;
    float4 sx0 = *(const float4*)(stt + 0*1024 + t*4);
    float4 sx1 = *(const float4*)(stt + 1*1024 + t*4);
    float4 sx2 = *(const float4*)(stt + 2*1024 + t*4);
    float4 sx3 = *(const float4*)(stt + 3*1024 + t*4);
    if (t < DD) ksx[t] = stt[DD*DD + t];
    __syncthreads();

    // ---- q row -> registers (serves phase 1 as c=lane and phase 2 as row=lane) ----
    float qreg[DD];
    #pragma unroll
    for (int d = 0; d < DD; ++d) qreg[d] = sq[lane*DP + d];   // 2-way banks, free
    __syncthreads();   // all qq reads done before S overwrites sq

    // ---- phase 1: scores S[c][r] = phi(q_c) . phi(k_r), masked r<=c ----
    #pragma unroll
    for (int j = 0; j < 16; ++j) {
        const int r = grp*16 + j;                       // wave-uniform
        const float4* kr = (const float4*)(buf + r*DD); // broadcast
        float s = 0.f;
        #pragma unroll
        for (int d4 = 0; d4 < 16; ++d4) {
            const float4 kk = kr[d4];
            s += qreg[d4*4+0]*kk.x + qreg[d4*4+1]*kk.y
               + qreg[d4*4+2]*kk.z + qreg[d4*4+3]*kk.w;
        }
        sq[lane*DP + r] = (r <= lane) ? s : 0.f;        // masked store, no phase-2 branch
    }
    __syncthreads();   // also guarantees kf reads done before buf overwrite

    // ---- S_excl regs -> buf (linear layout, conflict-free b128 writes) ----
    *(float4*)(buf + 0*1024 + t*4) = sx0;
    *(float4*)(buf + 1*1024 + t*4) = sx1;
    *(float4*)(buf + 2*1024 + t*4) = sx2;
    *(float4*)(buf + 3*1024 + t*4) = sx3;
    __syncthreads();

    // ---- phase 2: out[row, mq*16..+16) ----
    const int row = lane;
    const int mq  = grp;
    float acc[16];
    #pragma unroll
    for (int i = 0; i < 16; ++i) acc[i] = 0.f;
    float z = 0.f;

    // intra-chunk: acc += sum_r S[row][r] * v[r][m]; masked zeros keep z exact
    #pragma unroll 2
    for (int r = 0; r < CB; ++r) {
        const float s = sq[row*DP + r];                  // 2-way banks
        z += s;
        const float4* vr = (const float4*)(vv + r*DD + mq*16); // broadcast
        const float4 v0 = vr[0], v1 = vr[1], v2 = vr[2], v3 = vr[3];
        acc[0]  += s*v0.x; acc[1]  += s*v0.y; acc[2]  += s*v0.z; acc[3]  += s*v0.w;
        acc[4]  += s*v1.x; acc[5]  += s*v1.y; acc[6]  += s*v1.z; acc[7]  += s*v1.w;
        acc[8]  += s*v2.x; acc[9]  += s*v2.y; acc[10] += s*v2.z; acc[11] += s*v2.w;
        acc[12] += s*v3.x; acc[13] += s*v3.y; acc[14] += s*v3.z; acc[15] += s*v3.w;
    }

    // inter: acc += q . S_excl ; z += q . ksum_excl  (all indices compile-time)
    #pragma unroll
    for (int d4 = 0; d4 < 16; ++d4) {
        const float4 ks = *(const float4*)(ksx + d4*4);
        z += qreg[d4*4+0]*ks.x + qreg[d4*4+1]*ks.y
           + qreg[d4*4+2]*ks.z + qreg[d4*4+3]*ks.w;
        #pragma unroll
        for (int jd = 0; jd < 4; ++jd) {
            const int d = d4*4 + jd;
            const float qd = qreg[d];
            const float4* sr = (const float4*)(buf + d*DD + mq*16); // broadcast
            const float4 s0 = sr[0], s1 = sr[1], s2 = sr[2], s3 = sr[3];
            acc[0]  += qd*s0.x; acc[1]  += qd*s0.y; acc[2]  += qd*s0.z; acc[3]  += qd*s0.w;
            acc[4]  += qd*s1.x; acc[5]  += qd*s1.y; acc[6]  += qd*s1.z; acc[7]  += qd*s1.w;
            acc[8]  += qd*s2.x; acc[9]  += qd*s2.y; acc[10] += qd*s2.z; acc[11] += qd*s2.w;
            acc[12] += qd*s3.x; acc[13] += qd*s3.y; acc[14] += qd*s3.z; acc[15] += qd*s3.w;
        }
    }

    const float zinv = 1.0f / (z + 1e-6f);
    __syncthreads();   // all S_excl reads done before buf becomes out-stage

    // stage scaled output in LDS (padded), then coalesced global store
    #pragma unroll
    for (int jj = 0; jj < 16; ++jj)
        buf[row*DP + mq*16 + jj] = acc[jj] * zinv;       // 2-way banks
    __syncthreads();

    for (int i = t; i < CB*DD/4; i += 256) {
        const int r = i >> 4, c4 = i & 15;
        float4 o;
        o.x = buf[r*DP + c4*4 + 0];
        o.y = buf[r*DP + c4*4 + 1];
        o.z = buf[r*DP + c4*4 + 2];
        o.w = buf[r*DP + c4*4 + 3];
        *(float4*)(out + ((size_t)((n*LL + l0 + r)*NH + h))*DD + c4*4) = o;
    }
}

extern "C" void kernel_launch(void* const* d_in, const int* in_sizes, int n_in,
                              void* d_out, int out_size, void* d_ws, size_t ws_size,
                              hipStream_t stream) {
    const float* q = (const float*)d_in[0];
    const float* k = (const float*)d_in[1];
    const float* v = (const float*)d_in[2];
    float* out = (float*)d_out;
    float* ws  = (float*)d_ws;   // NB*NH*NG*SS*4 = ~24.4 MiB

    const int nblk = NB * NH * NG;   // 1536
    la_chunk_sums<<<nblk, 256, 0, stream>>>(k, v, ws);
    la_scan<<<NB*NH*5, 256, 0, stream>>>(ws);
    la_output<<<nblk, 256, 0, stream>>>(q, k, v, ws, out);
}

// Round 3
// 49.531 us; speedup vs baseline: 5.9721x; 1.9379x over previous
//
#include <hip/hip_runtime.h>

// Problem constants (match reference)
#define NB 4
#define LL 2048
#define NH 12
#define DD 64
#define CB 64              // chunk size (math identical to reference's 128)
#define NG (LL/CB)         // 32 chunks
#define SS (DD*DD + DD)    // per-chunk state: stateT[64][64] (m-major) + ksum[64]

typedef short bf16x8 __attribute__((ext_vector_type(8)));
typedef float f32x4  __attribute__((ext_vector_type(4)));

#define SWZ(row, x) ((x) ^ (((row) & 7) << 4))   // XOR-swizzle byte offset within 128B row

__device__ __forceinline__ float phi(float x) {
    return x > 0.0f ? x + 1.0f : __expf(x);      // elu(x)+1
}
__device__ __forceinline__ unsigned f2bf1(float x) {   // f32 -> bf16 bits (RNE)
    union { float f; unsigned u; } v; v.f = x;
    return (v.u + 0x7FFFu + ((v.u >> 16) & 1u)) >> 16;
}
__device__ __forceinline__ unsigned packbf(float a, float b) {
    return f2bf1(a) | (f2bf1(b) << 16);
}
__device__ __forceinline__ float bf2f(unsigned short u) {
    union { unsigned u; float f; } v; v.u = ((unsigned)u) << 16; return v.f;
}

// ---------------- Kernel 1: per-chunk stateT[m][d] = sum_r v[r][m] * phi(k)[r][d], + ksum[d]
__global__ __launch_bounds__(256) void la_chunk_sums(
    const float* __restrict__ kin, const float* __restrict__ vin,
    float* __restrict__ ws)
{
    __shared__ __align__(16) char sm[16384];   // KT [d][r] 0..8192 | VT [m][r] 8192..16384
    const int bid = blockIdx.x;
    const int g  = bid & (NG-1);
    const int h  = (bid / NG) % NH;
    const int n  = bid / (NG*NH);
    const int t  = threadIdx.x;
    const int l0 = g * CB;
    const int w   = t >> 6;
    const int l   = t & 63;
    const int gq  = l >> 4;     // quad id 0..3
    const int c16 = l & 15;

    #pragma unroll
    for (int p = 0; p < 4; ++p) {
        const int i = p*256 + t;
        const int r = i >> 4, c4 = i & 15;
        const size_t gidx = ((size_t)((n*LL + l0 + r)*NH + h))*DD + c4*4;
        float4 kk = *(const float4*)(kin + gidx);
        float4 vl = *(const float4*)(vin + gidx);
        const float kf[4] = {phi(kk.x), phi(kk.y), phi(kk.z), phi(kk.w)};
        const float vf[4] = {vl.x, vl.y, vl.z, vl.w};
        #pragma unroll
        for (int j = 0; j < 4; ++j) {
            const int d = c4*4 + j;
            *(unsigned short*)(sm +        d*128 + SWZ(d, 2*r)) = (unsigned short)f2bf1(kf[j]);
            *(unsigned short*)(sm + 8192 + d*128 + SWZ(d, 2*r)) = (unsigned short)f2bf1(vf[j]);
        }
    }
    __syncthreads();

    // wave w owns m-band [16w,16w+16)
    const int m = 16*w + c16;
    const bf16x8 va0 = *(const bf16x8*)(sm + 8192 + m*128 + SWZ(m,      gq*16));
    const bf16x8 va1 = *(const bf16x8*)(sm + 8192 + m*128 + SWZ(m, 64 + gq*16));
    f32x4 acc[4];
    #pragma unroll
    for (int td = 0; td < 4; ++td) { acc[td][0]=0.f; acc[td][1]=0.f; acc[td][2]=0.f; acc[td][3]=0.f; }
    #pragma unroll
    for (int td = 0; td < 4; ++td) {
        const int d = 16*td + c16;
        const bf16x8 kb0 = *(const bf16x8*)(sm + d*128 + SWZ(d,      gq*16));
        const bf16x8 kb1 = *(const bf16x8*)(sm + d*128 + SWZ(d, 64 + gq*16));
        acc[td] = __builtin_amdgcn_mfma_f32_16x16x32_bf16(va0, kb0, acc[td], 0, 0, 0);
        acc[td] = __builtin_amdgcn_mfma_f32_16x16x32_bf16(va1, kb1, acc[td], 0, 0, 0);
    }
    float* st = ws + (size_t)bid * SS;
    #pragma unroll
    for (int td = 0; td < 4; ++td)
        #pragma unroll
        for (int e = 0; e < 4; ++e) {
            const int mr = 16*w + 4*gq + e;           // C row = m
            st[mr*DD + 16*td + c16] = acc[td][e];     // C col = d; 64B-sector coalesced
        }
    if (t < DD) {    // ksum[d] = sum_r phi(k)[r][d]  (from bf16 KT, consistent with state)
        float s = 0.f;
        #pragma unroll 8
        for (int r = 0; r < CB; ++r)
            s += bf2f(*(const unsigned short*)(sm + t*128 + SWZ(t, 2*r)));
        st[DD*DD + t] = s;
    }
}

// ---------------- Kernel 2: exclusive prefix scan over chunks (per n,h), in place
__global__ __launch_bounds__(256) void la_scan(float* __restrict__ ws)
{
    const int nh = blockIdx.x / 5;
    const int sl = blockIdx.x % 5;
    const int t4 = sl*256 + threadIdx.x;
    if (t4 >= SS/4) return;
    float* base = ws + (size_t)nh * NG * SS + (size_t)t4 * 4;

    float4 run = make_float4(0.f, 0.f, 0.f, 0.f);
    #pragma unroll 1
    for (int g4 = 0; g4 < NG; g4 += 4) {
        float4 a0 = *(float4*)(base + (size_t)(g4+0)*SS);
        float4 a1 = *(float4*)(base + (size_t)(g4+1)*SS);
        float4 a2 = *(float4*)(base + (size_t)(g4+2)*SS);
        float4 a3 = *(float4*)(base + (size_t)(g4+3)*SS);
        *(float4*)(base + (size_t)(g4+0)*SS) = run;
        run.x += a0.x; run.y += a0.y; run.z += a0.z; run.w += a0.w;
        *(float4*)(base + (size_t)(g4+1)*SS) = run;
        run.x += a1.x; run.y += a1.y; run.z += a1.z; run.w += a1.w;
        *(float4*)(base + (size_t)(g4+2)*SS) = run;
        run.x += a2.x; run.y += a2.y; run.z += a2.z; run.w += a2.w;
        *(float4*)(base + (size_t)(g4+3)*SS) = run;
        run.x += a3.x; run.y += a3.y; run.z += a3.z; run.w += a3.w;
    }
}

// ---------------- Kernel 3: per-chunk output via MFMA
// smem: Q[c][d] 0..8K | K[r][d] 8..16K (S[c][r] after barrier) | VT[m][r] 16..24K
//       STX[m][d] 24..32K | KSX f32[64] | ZL f32[64]
#define SM_Q   0
#define SM_K   8192
#define SM_VT  16384
#define SM_STX 24576
#define SM_KSX 32768
#define SM_ZL  33024
#define SM_BYTES 33280

__global__ __launch_bounds__(256) void la_output(
    const float* __restrict__ qin, const float* __restrict__ kin,
    const float* __restrict__ vin, const float* __restrict__ ws,
    float* __restrict__ out)
{
    __shared__ __align__(16) char sm[SM_BYTES];
    const int bid = blockIdx.x;
    const int g  = bid & (NG-1);
    const int h  = (bid / NG) % NH;
    const int n  = bid / (NG*NH);
    const int t  = threadIdx.x;
    const int l0 = g * CB;
    const int w   = t >> 6;
    const int l   = t & 63;
    const int gq  = l >> 4;
    const int c16 = l & 15;

    // ---- stage phi(q), phi(k) row-major; v transposed; S_excl transposed; ksum ----
    #pragma unroll
    for (int p = 0; p < 4; ++p) {
        const int i = p*256 + t;
        const int row = i >> 4, c4 = i & 15;
        const size_t gidx = ((size_t)((n*LL + l0 + row)*NH + h))*DD + c4*4;
        float4 qq = *(const float4*)(qin + gidx);
        float4 kk = *(const float4*)(kin + gidx);
        float4 vl = *(const float4*)(vin + gidx);
        uint2 qp; qp.x = packbf(phi(qq.x), phi(qq.y)); qp.y = packbf(phi(qq.z), phi(qq.w));
        uint2 kp; kp.x = packbf(phi(kk.x), phi(kk.y)); kp.y = packbf(phi(kk.z), phi(kk.w));
        *(uint2*)(sm + SM_Q + row*128 + SWZ(row, c4*8)) = qp;
        *(uint2*)(sm + SM_K + row*128 + SWZ(row, c4*8)) = kp;
        const float vf[4] = {vl.x, vl.y, vl.z, vl.w};
        #pragma unroll
        for (int j = 0; j < 4; ++j) {
            const int m = c4*4 + j;
            *(unsigned short*)(sm + SM_VT + m*128 + SWZ(m, 2*row)) = (unsigned short)f2bf1(vf[j]);
        }
    }
    const float* stt = ws + (size_t)bid * SS;
    #pragma unroll
    for (int p = 0; p < 4; ++p) {
        const int i = p*256 + t;
        const int m = i >> 4, c4 = i & 15;
        const float4 sv = *(const float4*)(stt + m*DD + c4*4);   // stateT[m][d], coalesced
        uint2 sp; sp.x = packbf(sv.x, sv.y); sp.y = packbf(sv.z, sv.w);
        *(uint2*)(sm + SM_STX + m*128 + SWZ(m, c4*8)) = sp;
    }
    if (t < DD) ((float*)(sm + SM_KSX))[t] = stt[DD*DD + t];
    __syncthreads();

    // ---- q fragments (serve scores-B and inter-A); wave w owns c-band [16w,16w+16) ----
    const int c = 16*w + c16;
    const bf16x8 qf0 = *(const bf16x8*)(sm + SM_Q + c*128 + SWZ(c,      gq*16));
    const bf16x8 qf1 = *(const bf16x8*)(sm + SM_Q + c*128 + SWZ(c, 64 + gq*16));

    // ---- scores: S^T[r][c] = sum_d phi(k)[r][d] phi(q)[c][d], 4 r-tiles ----
    f32x4 sreg[4];
    #pragma unroll
    for (int tr = 0; tr < 4; ++tr) {
        const int r = 16*tr + c16;
        const bf16x8 ka0 = *(const bf16x8*)(sm + SM_K + r*128 + SWZ(r,      gq*16));
        const bf16x8 ka1 = *(const bf16x8*)(sm + SM_K + r*128 + SWZ(r, 64 + gq*16));
        f32x4 a; a[0]=0.f; a[1]=0.f; a[2]=0.f; a[3]=0.f;
        a = __builtin_amdgcn_mfma_f32_16x16x32_bf16(ka0, qf0, a, 0, 0, 0);
        a = __builtin_amdgcn_mfma_f32_16x16x32_bf16(ka1, qf1, a, 0, 0, 0);
        sreg[tr] = a;
    }
    // causal mask (keep r <= c) + z_intra partial
    float z = 0.f;
    #pragma unroll
    for (int tr = 0; tr < 4; ++tr)
        #pragma unroll
        for (int e = 0; e < 4; ++e) {
            const int rr = 16*tr + 4*gq + e;
            if (rr <= c) z += sreg[tr][e]; else sreg[tr][e] = 0.f;
        }
    // z_inter partial: this lane sums d in [16gq,16gq+16)
    #pragma unroll
    for (int dd = 0; dd < 16; ++dd) {
        const int d = 16*gq + dd;
        const float qv = bf2f(*(const unsigned short*)(sm + SM_Q + c*128 + SWZ(c, 2*d)));
        z += qv * ((const float*)(sm + SM_KSX))[d];
    }
    z += __shfl_xor(z, 16);
    z += __shfl_xor(z, 32);          // all lanes: z for column c
    __syncthreads();                  // all k reads complete before S overwrites K region

    // ---- write masked S (bf16) into K region as S[c][r], packed b64, swizzled ----
    #pragma unroll
    for (int tr = 0; tr < 4; ++tr) {
        uint2 sp; sp.x = packbf(sreg[tr][0], sreg[tr][1]); sp.y = packbf(sreg[tr][2], sreg[tr][3]);
        *(uint2*)(sm + SM_K + c*128 + SWZ(c, 32*tr + 8*gq)) = sp;
    }
    if (gq == 0) ((float*)(sm + SM_ZL))[c] = z;
    __syncthreads();

    // ---- PV intra + inter, accumulate out[c][m] ----
    const bf16x8 sf0 = *(const bf16x8*)(sm + SM_K + c*128 + SWZ(c,      gq*16));
    const bf16x8 sf1 = *(const bf16x8*)(sm + SM_K + c*128 + SWZ(c, 64 + gq*16));
    f32x4 acc[4];
    #pragma unroll
    for (int tm = 0; tm < 4; ++tm) { acc[tm][0]=0.f; acc[tm][1]=0.f; acc[tm][2]=0.f; acc[tm][3]=0.f; }
    #pragma unroll
    for (int tm = 0; tm < 4; ++tm) {
        const int m = 16*tm + c16;
        const bf16x8 vf0 = *(const bf16x8*)(sm + SM_VT + m*128 + SWZ(m,      gq*16));
        const bf16x8 vf1 = *(const bf16x8*)(sm + SM_VT + m*128 + SWZ(m, 64 + gq*16));
        acc[tm] = __builtin_amdgcn_mfma_f32_16x16x32_bf16(sf0, vf0, acc[tm], 0, 0, 0);
        acc[tm] = __builtin_amdgcn_mfma_f32_16x16x32_bf16(sf1, vf1, acc[tm], 0, 0, 0);
        const bf16x8 st0 = *(const bf16x8*)(sm + SM_STX + m*128 + SWZ(m,      gq*16));
        const bf16x8 st1 = *(const bf16x8*)(sm + SM_STX + m*128 + SWZ(m, 64 + gq*16));
        acc[tm] = __builtin_amdgcn_mfma_f32_16x16x32_bf16(qf0, st0, acc[tm], 0, 0, 0);
        acc[tm] = __builtin_amdgcn_mfma_f32_16x16x32_bf16(qf1, st1, acc[tm], 0, 0, 0);
    }

    // ---- epilogue: divide by z, scalar stores (4 full 64B sectors per instr) ----
    float zinv[4];
    #pragma unroll
    for (int e = 0; e < 4; ++e) {
        const float zr = ((const float*)(sm + SM_ZL))[16*w + 4*gq + e];  // broadcast
        zinv[e] = 1.0f / (zr + 1e-6f);
    }
    #pragma unroll
    for (int tm = 0; tm < 4; ++tm)
        #pragma unroll
        for (int e = 0; e < 4; ++e) {
            const int cr = 16*w + 4*gq + e;
            const int m  = 16*tm + c16;
            out[((size_t)((n*LL + l0 + cr)*NH + h))*DD + m] = acc[tm][e] * zinv[e];
        }
}

extern "C" void kernel_launch(void* const* d_in, const int* in_sizes, int n_in,
                              void* d_out, int out_size, void* d_ws, size_t ws_size,
                              hipStream_t stream) {
    const float* q = (const float*)d_in[0];
    const float* k = (const float*)d_in[1];
    const float* v = (const float*)d_in[2];
    float* out = (float*)d_out;
    float* ws  = (float*)d_ws;   // NB*NH*NG*SS*4 = ~24.4 MiB

    const int nblk = NB * NH * NG;   // 1536
    la_chunk_sums<<<nblk, 256, 0, stream>>>(k, v, ws);
    la_scan<<<NB*NH*5, 256, 0, stream>>>(ws);
    la_output<<<nblk, 256, 0, stream>>>(q, k, v, ws, out);
}

// Round 4
// 40.936 us; speedup vs baseline: 7.2260x; 1.2099x over previous
//
#include <hip/hip_runtime.h>

// Problem constants (match reference)
#define NB 4
#define LL 2048
#define NH 12
#define DD 64
#define CB 128                 // chunk size (== reference chunk; math identical)
#define NG (LL/CB)             // 16 chunks
#define NBH (NB*NH)            // 48
#define ST_BYTES (DD*DD*2)     // 8 KB: per-chunk state bf16 [m][d]
#define KS_BASE_BYTES ((size_t)NBH*NG*ST_BYTES)   // 6.29 MB, then ksum f32 region

typedef short bf16x8 __attribute__((ext_vector_type(8)));
typedef float f32x4  __attribute__((ext_vector_type(4)));

#define SWZ8(row, x)  ((x) ^ (((row) & 7) << 4))    // swizzle within 128B rows
#define SWZ16(row, x) ((x) ^ (((row) & 15) << 4))   // swizzle within 256B rows

__device__ __forceinline__ float phi(float x) {
    return x > 0.0f ? x + 1.0f : __expf(x);          // elu(x)+1
}
__device__ __forceinline__ unsigned f2bf1(float x) { // f32 -> bf16 bits (RNE)
    union { float f; unsigned u; } v; v.f = x;
    return (v.u + 0x7FFFu + ((v.u >> 16) & 1u)) >> 16;
}
__device__ __forceinline__ unsigned packbf(float a, float b) {
    return f2bf1(a) | (f2bf1(b) << 16);
}
__device__ __forceinline__ float bf2f(unsigned short u) {
    union { unsigned u; float f; } v; v.u = ((unsigned)u) << 16; return v.f;
}
__device__ __forceinline__ void addbf8(float* run, uint4 a) {
    const unsigned u[4] = {a.x, a.y, a.z, a.w};
    #pragma unroll
    for (int i = 0; i < 4; ++i) {
        run[2*i+0] += bf2f((unsigned short)(u[i] & 0xffffu));
        run[2*i+1] += bf2f((unsigned short)(u[i] >> 16));
    }
}
__device__ __forceinline__ uint4 pack8(const float* run) {
    uint4 s;
    s.x = packbf(run[0], run[1]); s.y = packbf(run[2], run[3]);
    s.z = packbf(run[4], run[5]); s.w = packbf(run[6], run[7]);
    return s;
}

// ---------------- Kernel 1: per-chunk stateT[m][d] = sum_r v[r][m]*phi(k)[r][d] (bf16)
//                  + ksum[d] = sum_r phi(k)[r][d] (f32, via ones-MFMA)
__global__ __launch_bounds__(256) void la_chunk_sums(
    const float* __restrict__ kin, const float* __restrict__ vin,
    char* __restrict__ wsb)
{
    __shared__ __align__(16) char sm[32768];  // KT [d][r] 0..16K | VT [m][r] 16..32K
    const int bid = blockIdx.x;
    const int g = bid & (NG-1);
    const int h = (bid >> 4) % NH;
    const int n = bid / (NG*NH);
    const int t = threadIdx.x;
    const int l0 = g * CB;
    const int w = t >> 6, l = t & 63, gq = l >> 4, c16 = l & 15;

    // stage phi(k), v transposed: [d][r], [m][r], 256B rows, SWZ16
    #pragma unroll
    for (int p = 0; p < 8; ++p) {
        const int i = p*256 + t;
        const int r = i >> 4, c4 = i & 15;
        const size_t gidx = ((size_t)((n*LL + l0 + r)*NH + h))*DD + c4*4;
        float4 kk = *(const float4*)(kin + gidx);
        float4 vl = *(const float4*)(vin + gidx);
        const float kf[4] = {phi(kk.x), phi(kk.y), phi(kk.z), phi(kk.w)};
        const float vf[4] = {vl.x, vl.y, vl.z, vl.w};
        #pragma unroll
        for (int j = 0; j < 4; ++j) {
            const int d = c4*4 + j;
            *(unsigned short*)(sm +         d*256 + SWZ16(d, 2*r)) = (unsigned short)f2bf1(kf[j]);
            *(unsigned short*)(sm + 16384 + d*256 + SWZ16(d, 2*r)) = (unsigned short)f2bf1(vf[j]);
        }
    }
    __syncthreads();

    const int m = 16*w + c16;
    bf16x8 va[4];
    #pragma unroll
    for (int ks = 0; ks < 4; ++ks)
        va[ks] = *(const bf16x8*)(sm + 16384 + m*256 + SWZ16(m, 64*ks + 16*gq));
    const short one = (short)0x3F80;
    const bf16x8 ones = {one, one, one, one, one, one, one, one};

    f32x4 acc[4], ksa[4];
    #pragma unroll
    for (int td = 0; td < 4; ++td) {
        acc[td][0]=0.f; acc[td][1]=0.f; acc[td][2]=0.f; acc[td][3]=0.f;
        ksa[td][0]=0.f; ksa[td][1]=0.f; ksa[td][2]=0.f; ksa[td][3]=0.f;
    }
    #pragma unroll
    for (int td = 0; td < 4; ++td) {
        const int d = 16*td + c16;
        #pragma unroll
        for (int ks = 0; ks < 4; ++ks) {
            const bf16x8 kb = *(const bf16x8*)(sm + d*256 + SWZ16(d, 64*ks + 16*gq));
            acc[td] = __builtin_amdgcn_mfma_f32_16x16x32_bf16(va[ks], kb, acc[td], 0, 0, 0);
            ksa[td] = __builtin_amdgcn_mfma_f32_16x16x32_bf16(ones,  kb, ksa[td], 0, 0, 0);
        }
    }
    __syncthreads();   // all KT/VT reads done before restage overwrites

    // restage state bf16 [m][d] into sm[0..8K) (128B rows, SWZ8)
    #pragma unroll
    for (int td = 0; td < 4; ++td)
        #pragma unroll
        for (int e = 0; e < 4; ++e) {
            const int mr = 16*w + 4*gq + e;
            const int d  = 16*td + c16;
            *(unsigned short*)(sm + mr*128 + SWZ8(mr, 2*d)) = (unsigned short)f2bf1(acc[td][e]);
        }
    if (w == 0 && gq == 0) {   // ksum f32 (all C-rows equal; take e=0)
        float* ksw = (float*)(wsb + KS_BASE_BYTES) + (size_t)((n*NH + h)*NG + g)*DD;
        #pragma unroll
        for (int td = 0; td < 4; ++td)
            ksw[16*td + c16] = ksa[td][0];
    }
    __syncthreads();

    char* stg = wsb + (size_t)((n*NH + h)*NG + g)*ST_BYTES;
    #pragma unroll
    for (int p = 0; p < 2; ++p) {
        const int i = p*256 + t;
        const int mr = i >> 3, cc = i & 7;
        *(uint4*)(stg + mr*128 + cc*16) = *(const uint4*)(sm + mr*128 + SWZ8(mr, cc*16));
    }
}

// ---------------- Kernel 2: exclusive prefix scan over chunks (per n,h), in place
// slices 0,1: state bf16 (f32 running sum in regs); slice 2: ksum f32
__global__ __launch_bounds__(256) void la_scan(char* __restrict__ wsb)
{
    const int nh = blockIdx.x / 3;
    const int sl = blockIdx.x % 3;
    const int t  = threadIdx.x;
    if (sl < 2) {
        const int t4 = sl*256 + t;                 // 0..511 uint4 slots of 8KB chunk
        char* base = wsb + (size_t)nh * NG * ST_BYTES + (size_t)t4 * 16;
        float run[8];
        #pragma unroll
        for (int i = 0; i < 8; ++i) run[i] = 0.f;
        #pragma unroll
        for (int g2 = 0; g2 < NG; g2 += 2) {
            uint4 a0 = *(uint4*)(base + (size_t)(g2+0)*ST_BYTES);
            uint4 a1 = *(uint4*)(base + (size_t)(g2+1)*ST_BYTES);
            *(uint4*)(base + (size_t)(g2+0)*ST_BYTES) = pack8(run);
            addbf8(run, a0);
            *(uint4*)(base + (size_t)(g2+1)*ST_BYTES) = pack8(run);
            addbf8(run, a1);
        }
    } else if (t < DD) {
        float* base = (float*)(wsb + KS_BASE_BYTES) + (size_t)nh * NG * DD + t;
        float run = 0.f;
        #pragma unroll
        for (int g4 = 0; g4 < NG; g4 += 4) {
            float a0 = base[(g4+0)*DD], a1 = base[(g4+1)*DD];
            float a2 = base[(g4+2)*DD], a3 = base[(g4+3)*DD];
            base[(g4+0)*DD] = run; run += a0;
            base[(g4+1)*DD] = run; run += a1;
            base[(g4+2)*DD] = run; run += a2;
            base[(g4+3)*DD] = run; run += a3;
        }
    }
}

// ---------------- Kernel 3: per-chunk output via MFMA, 512 threads (8 waves)
// LDS: Q[c][d] 0..16K, K[r][d] 16..32K (S[c][r] overlays 0..32K after scores),
//      VT[m][r] 32..48K, STX[m][d] 48..56K, KSX f32[64], ZL f32[128]
#define SM_Q   0
#define SM_K   16384
#define SM_S   0
#define SM_VT  32768
#define SM_STX 49152
#define SM_KSX 57344
#define SM_ZL  57600
#define SM_BYTES 58112

__global__ __launch_bounds__(512) void la_output(
    const float* __restrict__ qin, const float* __restrict__ kin,
    const float* __restrict__ vin, const char* __restrict__ wsb,
    float* __restrict__ out)
{
    __shared__ __align__(16) char sm[SM_BYTES];
    const int bid = blockIdx.x;
    const int g = bid & (NG-1);
    const int h = (bid >> 4) % NH;
    const int n = bid / (NG*NH);
    const int t = threadIdx.x;
    const int l0 = g * CB;
    const int w = t >> 6, l = t & 63, gq = l >> 4, c16 = l & 15;
    const int c = 16*w + c16;            // this lane's column (query row) 0..127

    // ---- stage phi(q),phi(k) row-major (SWZ8); v transposed (SWZ16) ----
    #pragma unroll
    for (int p = 0; p < 4; ++p) {
        const int i = p*512 + t;
        const int r = i >> 4, c4 = i & 15;
        const size_t gidx = ((size_t)((n*LL + l0 + r)*NH + h))*DD + c4*4;
        float4 qq = *(const float4*)(qin + gidx);
        float4 kk = *(const float4*)(kin + gidx);
        float4 vl = *(const float4*)(vin + gidx);
        uint2 qp; qp.x = packbf(phi(qq.x), phi(qq.y)); qp.y = packbf(phi(qq.z), phi(qq.w));
        uint2 kp; kp.x = packbf(phi(kk.x), phi(kk.y)); kp.y = packbf(phi(kk.z), phi(kk.w));
        *(uint2*)(sm + SM_Q + r*128 + SWZ8(r, c4*8)) = qp;
        *(uint2*)(sm + SM_K + r*128 + SWZ8(r, c4*8)) = kp;
        const float vf[4] = {vl.x, vl.y, vl.z, vl.w};
        #pragma unroll
        for (int j = 0; j < 4; ++j) {
            const int m = c4*4 + j;
            *(unsigned short*)(sm + SM_VT + m*256 + SWZ16(m, 2*r)) = (unsigned short)f2bf1(vf[j]);
        }
    }
    // state bf16 (already exclusive-scanned): linear -> STX swizzled
    {
        const char* stg = wsb + (size_t)((n*NH + h)*NG + g)*ST_BYTES;
        const int mr = t >> 3, cc = t & 7;
        *(uint4*)(sm + SM_STX + mr*128 + SWZ8(mr, cc*16)) = *(const uint4*)(stg + mr*128 + cc*16);
    }
    if (t < DD)
        ((float*)(sm + SM_KSX))[t] =
            ((const float*)(wsb + KS_BASE_BYTES))[(size_t)((n*NH + h)*NG + g)*DD + t];
    __syncthreads();

    // ---- q fragments (kept in regs through both phases) ----
    const bf16x8 qf0 = *(const bf16x8*)(sm + SM_Q + c*128 + SWZ8(c, 16*gq));
    const bf16x8 qf1 = *(const bf16x8*)(sm + SM_Q + c*128 + SWZ8(c, 64 + 16*gq));

    // ---- scores: S^T tiles, 8 r-tiles of 16 ----
    f32x4 sreg[8];
    #pragma unroll
    for (int tr = 0; tr < 8; ++tr) {
        const int r = 16*tr + c16;
        const bf16x8 ka0 = *(const bf16x8*)(sm + SM_K + r*128 + SWZ8(r, 16*gq));
        const bf16x8 ka1 = *(const bf16x8*)(sm + SM_K + r*128 + SWZ8(r, 64 + 16*gq));
        f32x4 a; a[0]=0.f; a[1]=0.f; a[2]=0.f; a[3]=0.f;
        a = __builtin_amdgcn_mfma_f32_16x16x32_bf16(ka0, qf0, a, 0, 0, 0);
        a = __builtin_amdgcn_mfma_f32_16x16x32_bf16(ka1, qf1, a, 0, 0, 0);
        sreg[tr] = a;
    }
    // causal mask (keep r <= c) + z intra partial
    float z = 0.f;
    #pragma unroll
    for (int tr = 0; tr < 8; ++tr)
        #pragma unroll
        for (int e = 0; e < 4; ++e) {
            const int rr = 16*tr + 4*gq + e;
            if (rr <= c) z += sreg[tr][e]; else sreg[tr][e] = 0.f;
        }
    // z inter partial from qf regs (lane holds d=8gq+[0,8) and 32+8gq+[0,8))
    {
        const float* ksxf = (const float*)(sm + SM_KSX);
        #pragma unroll
        for (int i = 0; i < 8; ++i) {
            z += bf2f((unsigned short)qf0[i]) * ksxf[8*gq + i];
            z += bf2f((unsigned short)qf1[i]) * ksxf[32 + 8*gq + i];
        }
    }
    z += __shfl_xor(z, 16);
    z += __shfl_xor(z, 32);
    __syncthreads();   // all Q/K LDS reads done before S overlays them

    // ---- write masked S bf16 as S[c][r] (256B rows, SWZ16) ----
    #pragma unroll
    for (int tr = 0; tr < 8; ++tr) {
        uint2 sp; sp.x = packbf(sreg[tr][0], sreg[tr][1]); sp.y = packbf(sreg[tr][2], sreg[tr][3]);
        *(uint2*)(sm + SM_S + c*256 + SWZ16(c, 32*tr + 8*gq)) = sp;
    }
    if (gq == 0) ((float*)(sm + SM_ZL))[c] = z;
    __syncthreads();

    // ---- PV intra (k=r, 4 steps) + inter (k=d, 2 steps) ----
    bf16x8 sf[4];
    #pragma unroll
    for (int ks = 0; ks < 4; ++ks)
        sf[ks] = *(const bf16x8*)(sm + SM_S + c*256 + SWZ16(c, 64*ks + 16*gq));
    f32x4 acc[4];
    #pragma unroll
    for (int tm = 0; tm < 4; ++tm) { acc[tm][0]=0.f; acc[tm][1]=0.f; acc[tm][2]=0.f; acc[tm][3]=0.f; }
    #pragma unroll
    for (int tm = 0; tm < 4; ++tm) {
        const int m = 16*tm + c16;
        #pragma unroll
        for (int ks = 0; ks < 4; ++ks) {
            const bf16x8 vf = *(const bf16x8*)(sm + SM_VT + m*256 + SWZ16(m, 64*ks + 16*gq));
            acc[tm] = __builtin_amdgcn_mfma_f32_16x16x32_bf16(sf[ks], vf, acc[tm], 0, 0, 0);
        }
        const bf16x8 st0 = *(const bf16x8*)(sm + SM_STX + m*128 + SWZ8(m, 16*gq));
        const bf16x8 st1 = *(const bf16x8*)(sm + SM_STX + m*128 + SWZ8(m, 64 + 16*gq));
        acc[tm] = __builtin_amdgcn_mfma_f32_16x16x32_bf16(qf0, st0, acc[tm], 0, 0, 0);
        acc[tm] = __builtin_amdgcn_mfma_f32_16x16x32_bf16(qf1, st1, acc[tm], 0, 0, 0);
    }

    // ---- epilogue ----
    float zinv[4];
    #pragma unroll
    for (int e = 0; e < 4; ++e) {
        const float zr = ((const float*)(sm + SM_ZL))[16*w + 4*gq + e];
        zinv[e] = 1.0f / (zr + 1e-6f);
    }
    #pragma unroll
    for (int tm = 0; tm < 4; ++tm)
        #pragma unroll
        for (int e = 0; e < 4; ++e) {
            const int cr = 16*w + 4*gq + e;
            const int m  = 16*tm + c16;
            out[((size_t)((n*LL + l0 + cr)*NH + h))*DD + m] = acc[tm][e] * zinv[e];
        }
}

extern "C" void kernel_launch(void* const* d_in, const int* in_sizes, int n_in,
                              void* d_out, int out_size, void* d_ws, size_t ws_size,
                              hipStream_t stream) {
    const float* q = (const float*)d_in[0];
    const float* k = (const float*)d_in[1];
    const float* v = (const float*)d_in[2];
    float* out = (float*)d_out;
    char* wsb  = (char*)d_ws;   // state bf16 6.29 MB + ksum f32 0.2 MB

    const int nblk = NB * NH * NG;   // 768
    la_chunk_sums<<<nblk, 256, 0, stream>>>(k, v, wsb);
    la_scan<<<NBH*3, 256, 0, stream>>>(wsb);
    la_output<<<nblk, 512, 0, stream>>>(q, k, v, wsb, out);
}